// Round 4
// baseline (307.647 us; speedup 1.0000x reference)
//
#include <hip/hip_runtime.h>

#define CRF_B 1024
#define CRF_T 512
#define CRF_K 64
#define CRF_START 62
#define CRF_STOP 63

typedef _Float16 hh2 __attribute__((ext_vector_type(2)));
typedef unsigned int vu16 __attribute__((ext_vector_type(16)));
typedef float vf16 __attribute__((ext_vector_type(16)));

#if __has_builtin(__builtin_amdgcn_fdot2)
#define USE_DOT2 1
#else
#define USE_DOT2 0
#endif

__device__ __forceinline__ float bcastf(float v, int lane) {
  return __int_as_float(__builtin_amdgcn_readlane(__float_as_int(v), lane));
}

// DPP helpers (VALU pipe, no LDS): update_dpp needs compile-time ctrl/masks
#define DPP_F(x, ctrl, rmask)                                                 \
  __int_as_float(__builtin_amdgcn_update_dpp(0, __float_as_int(x), ctrl,      \
                                             rmask, 0xf, true))

__device__ __forceinline__ float wave_sum64(float v) {
#pragma unroll
  for (int off = 32; off > 0; off >>= 1) v += __shfl_xor(v, off, 64);
  return v;
}

// One block per batch: wave0 = forward recurrence (exp domain, f16 dot2),
// wave1 = gold-path score (fully parallel). out += (fwd - gold)/B.
__global__ __launch_bounds__(128, 1) void crf_kernel(
    const float* __restrict__ feats, const int* __restrict__ lengths,
    const int* __restrict__ tags, const float* __restrict__ trans,
    float* __restrict__ out) {
  __shared__ float sT[CRF_K * 65];  // stride 65: conflict-free + gold reads

  const int b = blockIdx.x;
  const int tid = threadIdx.x;
  const int lane = tid & 63;

  for (int idx = tid; idx < CRF_K * CRF_K; idx += 128)
    sT[(idx >> 6) * 65 + (idx & 63)] = trans[idx];
  __syncthreads();

  const int L = lengths[b];

  if (tid < 64) {
    // ---------------- forward wave ----------------
    // E row i as 32 packed f16 pairs (32 VGPRs, halves R3's AGPR-demotion
    // pressure). exp(-10000)=0 -> column STOP and row START are exact zeros.
    const float* trow = &sT[lane * 65];
#if USE_DOT2
    vu16 EA, EB;
#pragma unroll
    for (int jp = 0; jp < 16; ++jp) {
      hh2 v;
      v.x = (_Float16)__expf(trow[2 * jp]);
      v.y = (_Float16)__expf(trow[2 * jp + 1]);
      EA[jp] = __builtin_bit_cast(unsigned int, v);
    }
#pragma unroll
    for (int jp = 0; jp < 16; ++jp) {
      hh2 v;
      v.x = (_Float16)__expf(trow[32 + 2 * jp]);
      v.y = (_Float16)__expf(trow[32 + 2 * jp + 1]);
      EB[jp] = __builtin_bit_cast(unsigned int, v);
    }
#else
    vf16 E0, E1, E2, E3;
#pragma unroll
    for (int j = 0; j < 16; ++j) E0[j] = __expf(trow[j]);
#pragma unroll
    for (int j = 0; j < 16; ++j) E1[j] = __expf(trow[16 + j]);
#pragma unroll
    for (int j = 0; j < 16; ++j) E2[j] = __expf(trow[32 + j]);
#pragma unroll
    for (int j = 0; j < 16; ++j) E3[j] = __expf(trow[48 + j]);
#endif

    const float* bfeats = feats + (size_t)b * CRF_T * CRF_K + lane;

    float P = (lane == CRF_START) ? 1.0f : 0.0f;  // exp-domain state
    int offs = 0;                                 // P_true = P * 2^offs

    float e[8], f[8];
#pragma unroll
    for (int r = 0; r < 8; ++r) e[r] = bfeats[r * CRF_K];

    auto do_step = [&](float ee) {
      // wave-max via DPP tree (all VALU; excluded lanes see old=0, P>=0 ok)
      float m = P;
      m = fmaxf(m, DPP_F(m, 0x111, 0xf));  // row_shr:1
      m = fmaxf(m, DPP_F(m, 0x112, 0xf));  // row_shr:2
      m = fmaxf(m, DPP_F(m, 0x114, 0xf));  // row_shr:4
      m = fmaxf(m, DPP_F(m, 0x118, 0xf));  // row_shr:8
      m = fmaxf(m, DPP_F(m, 0x142, 0xa));  // row_bcast15 -> rows 1,3
      m = fmaxf(m, DPP_F(m, 0x143, 0xc));  // row_bcast31 -> rows 2,3
      float mx = bcastf(m, 63);
      // exponent-only normalize: exact offset accounting, no rcp/log on chain
      int ex = ((__float_as_int(mx) >> 23) & 0xff) - 126;  // mx*2^-ex in [.5,1)
      offs += ex;
      float Pn = P * __int_as_float((127 - ex) << 23);  // 2^-ex
#if USE_DOT2
      // pack (Pn[2k],Pn[2k+1]) as f16x2 in even lanes: cvt + quad_perm + pack
      _Float16 h = (_Float16)Pn;
      int hi = (int)(unsigned short)__builtin_bit_cast(unsigned short, h);
      int hn = __builtin_amdgcn_update_dpp(0, hi, 0xB1, 0xf, 0xf, true);  // xor1
      hh2 hp;
      hp.x = h;
      hp.y = __builtin_bit_cast(_Float16, (unsigned short)hn);
      int hpi = __builtin_bit_cast(int, hp);
      // 32 broadcasts + 32 dots, readlane pipelined 4 ahead of consuming dot
      int rl[4];
#pragma unroll
      for (int q = 0; q < 4; ++q) rl[q] = __builtin_amdgcn_readlane(hpi, 2 * q);
      float a0 = 0.f, a1 = 0.f, a2 = 0.f, a3 = 0.f;
#pragma unroll
      for (int jp = 0; jp < 32; ++jp) {
        int cur = rl[jp & 3];
        if (jp + 4 < 32)
          rl[jp & 3] = __builtin_amdgcn_readlane(hpi, 2 * (jp + 4));
        hh2 pb = __builtin_bit_cast(hh2, cur);
        hh2 ev = __builtin_bit_cast(hh2, (jp < 16) ? EA[jp] : EB[jp - 16]);
        float* acc = (jp & 3) == 0 ? &a0 : ((jp & 3) == 1 ? &a1 : ((jp & 3) == 2 ? &a2 : &a3));
        *acc = __builtin_amdgcn_fdot2(ev, pb, *acc, false);
      }
      P = ((a0 + a1) + (a2 + a3)) * ee;
#else
      float a0 = 0.f, a1 = 0.f, a2 = 0.f, a3 = 0.f;
#pragma unroll
      for (int j = 0; j < 16; ++j) a0 = __builtin_fmaf(E0[j], bcastf(Pn, j), a0);
#pragma unroll
      for (int j = 0; j < 16; ++j) a1 = __builtin_fmaf(E1[j], bcastf(Pn, 16 + j), a1);
#pragma unroll
      for (int j = 0; j < 16; ++j) a2 = __builtin_fmaf(E2[j], bcastf(Pn, 32 + j), a2);
#pragma unroll
      for (int j = 0; j < 15; ++j) a3 = __builtin_fmaf(E3[j], bcastf(Pn, 48 + j), a3);
      P = ((a0 + a1) + (a2 + a3)) * ee;
#endif
    };

    const int Lb = L & ~7;
    for (int t0 = 0; t0 < Lb; t0 += 8) {
      const int tn = t0 + 8;
      if (tn < CRF_T) {  // prefetch next 8 emits (wave-uniform branch)
#pragma unroll
        for (int r = 0; r < 8; ++r) f[r] = bfeats[(tn + r) * CRF_K];
      } else {
#pragma unroll
        for (int r = 0; r < 8; ++r) f[r] = 0.0f;
      }
      float ee[8];
#pragma unroll
      for (int r = 0; r < 8; ++r) ee[r] = __expf(e[r]);  // off-chain
#pragma unroll
      for (int r = 0; r < 8; ++r) do_step(ee[r]);
#pragma unroll
      for (int r = 0; r < 8; ++r) e[r] = f[r];
    }
    if (Lb < L) {
#pragma unroll
      for (int r = 0; r < 8; ++r)
        if (Lb + r < L) do_step(__expf(e[r]));
    }

    // terminal: fwd = offs*ln2 + log( sum_i P[i]*exp(trans[STOP][i]) )
    float eST = __expf(sT[CRF_STOP * 65 + lane]);
    float s2 = wave_sum64(P * eST);
    float fwd = (float)offs * 0.69314718056f + __logf(s2);
    if (lane == 0) atomicAdd(out, fwd * (1.0f / CRF_B));
  } else {
    // ---------------- gold wave (fully parallel) ----------------
    const int* btags = tags + b * CRF_T;
    const float* bf = feats + (size_t)b * CRF_T * CRF_K;
    float gold = 0.0f;
#pragma unroll
    for (int base = 0; base < CRF_T; base += 64) {
      int t = base + lane;
      if (t < L) {
        int tg = btags[t];
        int tp = (t == 0) ? CRF_START : btags[t - 1];
        gold += bf[(size_t)t * CRF_K + tg];  // emit
        gold += sT[tg * 65 + tp];            // transition
      }
    }
    gold = wave_sum64(gold);
    if (lane == 0) {
      gold += sT[CRF_STOP * 65 + btags[L - 1]];  // terminal transition
      atomicAdd(out, -gold * (1.0f / CRF_B));
    }
  }
}

extern "C" void kernel_launch(void* const* d_in, const int* in_sizes, int n_in,
                              void* d_out, int out_size, void* d_ws, size_t ws_size,
                              hipStream_t stream) {
  const float* feats = (const float*)d_in[0];
  const int* lengths = (const int*)d_in[1];
  const int* tags = (const int*)d_in[2];
  const float* trans = (const float*)d_in[3];
  float* out = (float*)d_out;
  hipMemsetAsync(out, 0, sizeof(float), stream);
  crf_kernel<<<CRF_B, 128, 0, stream>>>(feats, lengths, tags, trans, out);
}